// Round 2
// baseline (316.477 us; speedup 1.0000x reference)
//
#include <hip/hip_runtime.h>
#include <hip/hip_bf16.h>
#include <math.h>

#define HIDDEN   2048
#define NEXPERT  64
#define TOPK     8
#define TPW      8        // tokens per wave
#define KCHUNK   256      // k-interleave chunk: keeps phase-B uniform reads L2-hot
#define RSQRT_H  0.02209708691207961f   // 1/sqrt(2048)

// W'[e,k] = proj_w[e,k] * scale[k] * H^-0.5  (folds elementwise scale + root-size scaling)
__global__ __launch_bounds__(256) void prep_w_kernel(
    const float* __restrict__ w, const float* __restrict__ scale,
    float* __restrict__ wp)
{
    int i = blockIdx.x * 256 + threadIdx.x;
    wp[i] = w[i] * scale[i & (HIDDEN - 1)] * RSQRT_H;
}

__global__ __launch_bounds__(256) void router_kernel(
    const float* __restrict__ h, const float* __restrict__ wp,
    const float* __restrict__ pes,
    float* __restrict__ out_w, float* __restrict__ out_i, float* __restrict__ out_c)
{
    const int lane = (int)threadIdx.x & 63;
    // wave-uniform wave id -> uniform h addresses (enables scalar loads / broadcast)
    const int wid  = __builtin_amdgcn_readfirstlane((int)(blockIdx.x * 4u) + ((int)threadIdx.x >> 6));
    const int t0   = wid * TPW;

    __shared__ int hist[NEXPERT];
    if (threadIdx.x < NEXPERT) hist[threadIdx.x] = 0;
    __syncthreads();

    const float* __restrict__ hbase = h + (size_t)t0 * HIDDEN;
    const float* __restrict__ wrow  = wp + (size_t)lane * HIDDEN;   // lane = expert

    float  ss[TPW];     // sum-of-squares lane partials (lane-split over k)
    float  acc[TPW];    // fp32 chunk accumulator (32-k chunks)
    double accd[TPW];   // f64 running dot -> ordering-exact logits
#pragma unroll
    for (int t = 0; t < TPW; ++t) { ss[t] = 0.f; acc[t] = 0.f; accd[t] = 0.0; }

    for (int kc0 = 0; kc0 < HIDDEN; kc0 += KCHUNK) {
        // Phase A: coalesced float4 loads, sum-of-squares; also warms L2 for phase B
#pragma unroll
        for (int t = 0; t < TPW; ++t) {
            float4 v = *(const float4*)(hbase + t * HIDDEN + kc0 + lane * 4);
            ss[t] = fmaf(v.x, v.x, ss[t]);
            ss[t] = fmaf(v.y, v.y, ss[t]);
            ss[t] = fmaf(v.z, v.z, ss[t]);
            ss[t] = fmaf(v.w, v.w, ss[t]);
        }
        // Phase B: dots. h wave-uniform (1 fmac feeds all 64 experts), W' per-lane rows.
        for (int kc = kc0; kc < kc0 + KCHUNK; kc += 32) {
#pragma unroll
            for (int kk = 0; kk < 32; kk += 8) {
                float4 w0 = *(const float4*)(wrow + kc + kk);
                float4 w1 = *(const float4*)(wrow + kc + kk + 4);
#pragma unroll
                for (int t = 0; t < TPW; ++t) {
                    const float* hp = hbase + t * HIDDEN + kc + kk;
                    float4 ha = *(const float4*)hp;
                    float4 hb = *(const float4*)(hp + 4);
                    float a = acc[t];
                    a = fmaf(ha.x, w0.x, a);
                    a = fmaf(ha.y, w0.y, a);
                    a = fmaf(ha.z, w0.z, a);
                    a = fmaf(ha.w, w0.w, a);
                    a = fmaf(hb.x, w1.x, a);
                    a = fmaf(hb.y, w1.y, a);
                    a = fmaf(hb.z, w1.z, a);
                    a = fmaf(hb.w, w1.w, a);
                    acc[t] = a;
                }
            }
            // fold 32-k chunk into f64 total: logit error ~1e-9 << order-stat gaps ~1.7e-3
#pragma unroll
            for (int t = 0; t < TPW; ++t) { accd[t] += (double)acc[t]; acc[t] = 0.f; }
        }
    }

#pragma unroll
    for (int t = 0; t < TPW; ++t) {
        // finalize RMS factor (uniform per token -> cannot affect top-k order)
        float s = ss[t];
#pragma unroll
        for (int off = 32; off; off >>= 1) s += __shfl_xor(s, off, 64);
        float r = (float)(1.0 / sqrt((double)s * (1.0 / (double)HIDDEN) + 1e-6));
        float logit = (float)accd[t] * r;

        // iterative top-8: descending, exact ties -> lowest expert index (jax semantics)
        float work = logit;
        float myval = 0.f; int myidx = 0; float m0 = 0.f;
#pragma unroll
        for (int i = 0; i < TOPK; ++i) {
            float mx = work;
#pragma unroll
            for (int off = 32; off; off >>= 1) mx = fmaxf(mx, __shfl_xor(mx, off, 64));
            unsigned long long msk = __ballot(work == mx);
            int src = __ffsll((long long)msk) - 1;
            if (i == 0) m0 = mx;
            if (lane == i) { myval = mx; myidx = src; }
            if (lane == src) work = -3.402823466e38f;
        }

        // softmax denominator cancels vs top-k renorm: w_i = exp(l_i-m0)/sum_top8
        float ev = (lane < TOPK) ? expf(myval - m0) : 0.f;
        float es = ev;
        es += __shfl_xor(es, 1, 64);
        es += __shfl_xor(es, 2, 64);
        es += __shfl_xor(es, 4, 64);
        if (lane < TOPK) {
            float wgt = (ev / es) * pes[myidx];
            size_t o = (size_t)(t0 + t) * TOPK + lane;
            out_w[o] = wgt;
            // harness reads the whole d_out as float32: indices must be written as floats
            out_i[o] = (float)myidx;
            atomicAdd(&hist[myidx], 1);
        }
    }

    __syncthreads();
    if (threadIdx.x < NEXPERT) {
        atomicAdd(&out_c[threadIdx.x], (float)hist[threadIdx.x]);
    }
}

extern "C" void kernel_launch(void* const* d_in, const int* in_sizes, int n_in,
                              void* d_out, int out_size, void* d_ws, size_t ws_size,
                              hipStream_t stream) {
    const float* h     = (const float*)d_in[0];   // [4,4096,2048] f32
    const float* scale = (const float*)d_in[1];   // [2048] f32
    const float* w     = (const float*)d_in[2];   // [64,2048] f32
    const float* pes   = (const float*)d_in[3];   // [64] f32

    const int tokens = in_sizes[0] / HIDDEN;      // 16384

    float* wp = (float*)d_ws;                     // 64*2048 f32 = 512 KB scratch

    float* out_w = (float*)d_out;                                   // [tokens,8] f32
    float* out_i = (float*)d_out + (size_t)tokens * TOPK;           // [tokens,8] indices-as-f32
    float* out_c = (float*)d_out + (size_t)tokens * TOPK * 2;       // [64] f32

    // counts region is re-poisoned before every timed launch -> zero it (capturable)
    hipMemsetAsync(out_c, 0, NEXPERT * sizeof(float), stream);

    prep_w_kernel<<<(NEXPERT * HIDDEN) / 256, 256, 0, stream>>>(w, scale, wp);

    // 8 tokens/wave, 4 waves/block -> 32 tokens/block
    router_kernel<<<tokens / 32, 256, 0, stream>>>(h, wp, pes, out_w, out_i, out_c);
}